// Round 11
// baseline (217.800 us; speedup 1.0000x reference)
//
#include <hip/hip_runtime.h>
#include <hip/hip_bf16.h>
#include <hip/hip_fp16.h>

#define N_NODES 50000
#define N_EDGES 640000
#define E_TOT   690000   // edges + self-loops
#define CH      128
#define GEMMB   782                       // 3125 row-tiles / 4 waves, +1
#define EBLK    2048                      // edges per hist/bucket block
#define NEB     337                       // ceil(E_TOT / EBLK)
#define NBUCK   196                       // ceil(N_NODES / 256)
#define MTP     344                       // MT row pitch (>= NEB)

typedef __attribute__((ext_vector_type(8))) short short8;
typedef __attribute__((ext_vector_type(4))) float float4v;
typedef __attribute__((ext_vector_type(4))) unsigned short us4;

static __device__ __forceinline__ float bf2f(unsigned short u) {
  return __uint_as_float(((unsigned)u) << 16);
}
static __device__ __forceinline__ unsigned short f2bf(float f) {
  unsigned u = __float_as_uint(f);
  return (unsigned short)((u + 0x7fffu + ((u >> 16) & 1u)) >> 16);
}

// ---- runtime dtype detection (parallel, 1 block) ------------------------
__global__ void k_detect(const unsigned short* __restrict__ x16,
                         const unsigned int* __restrict__ eiw,
                         int* __restrict__ flags)
{
  __shared__ int sf32, si64;
  int t = threadIdx.x;
  if (t == 0) { sf32 = 0; si64 = 1; }
  __syncthreads();
  int bad = 0;
  for (int i = t; i < 4096; i += 256) {
    float v = bf2f(x16[i]);
    if (!(v == v) || fabsf(v) > 100.f) bad = 1;
  }
  if (bad) atomicOr(&sf32, 1);
  if (t < 128 && eiw[2 * t + 1] != 0u) atomicAnd(&si64, 0);
  __syncthreads();
  if (t == 0) { flags[0] = sf32; flags[1] = si64; }
}

static __device__ __forceinline__ void load_edge(const int* __restrict__ ei,
                                                 int e, int i64, int& s, int& d)
{
  if (e >= N_EDGES) { s = d = e - N_EDGES; return; }
  if (i64) { s = ei[2 * (size_t)e]; d = ei[2 * ((size_t)N_EDGES + e)]; }
  else     { s = ei[e];             d = ei[N_EDGES + e]; }
}

static __device__ __forceinline__ short8 load_bf8(const void* __restrict__ X,
                                                  size_t off, int f32)
{
  if (!f32) return *(const short8*)((const unsigned short*)X + off);
  const float4* p = (const float4*)((const float*)X + off);
  float4 u = p[0], v = p[1];
  short8 r;
  r[0] = (short)f2bf(u.x); r[1] = (short)f2bf(u.y);
  r[2] = (short)f2bf(u.z); r[3] = (short)f2bf(u.w);
  r[4] = (short)f2bf(v.x); r[5] = (short)f2bf(v.y);
  r[6] = (short)f2bf(v.z); r[7] = (short)f2bf(v.w);
  return r;
}

// ---- prep: transpose W -> Wt_g[c][k]; Ba_g[n][k] = sum_c W[k][c]*a[n][c] --
__global__ __launch_bounds__(256) void k_prep(
    const void* __restrict__ W1, const void* __restrict__ W2,
    const void* __restrict__ as1, const void* __restrict__ ad1,
    const void* __restrict__ as2, const void* __restrict__ ad2,
    unsigned short* __restrict__ Wt1, unsigned short* __restrict__ Wt2,
    unsigned short* __restrict__ Ba1, unsigned short* __restrict__ Ba2,
    const int* __restrict__ flags)
{
  int f32 = flags[0];
  int b = blockIdx.x, t = threadIdx.x;
  if (b < 8) {
    int g = b * 256 + t;          // 0..2047
    int l = g >> 10;
    int rem = g & 1023;
    int k = rem >> 3, n = rem & 7;
    const void* W  = l ? W2 : W1;
    const void* av = (n < 4) ? (l ? as2 : as1) : (l ? ad2 : ad1);
    int h = n & 3;
    float sum = 0.f;
    for (int c = 0; c < 32; c++) {
      float w = f32 ? ((const float*)W)[k * 128 + h * 32 + c]
                    : bf2f(((const unsigned short*)W)[k * 128 + h * 32 + c]);
      float a = f32 ? ((const float*)av)[h * 32 + c]
                    : bf2f(((const unsigned short*)av)[h * 32 + c]);
      sum += w * a;
    }
    unsigned short* Ba = l ? Ba2 : Ba1;
    Ba[n * 128 + k] = f2bf(sum);
    Ba[(8 + (rem >> 7)) * 128 + (rem & 127)] = 0;   // zero rows 8..15
  } else {
    int b2 = b - 8;
    int l = b2 >> 7, c = b2 & 127;
    if (t < 128) {
      const void* W = l ? W2 : W1;
      unsigned short* Wt = l ? Wt2 : Wt1;
      Wt[c * 128 + t] = f32 ? f2bf(((const float*)W)[t * 128 + c])
                            : ((const unsigned short*)W)[t * 128 + c];
    }
  }
}

// ---- shared GEMM body: H = X @ W + fused alpha via extra MFMA column ----
struct SmemG { unsigned short WB[144][136]; };

static __device__ __forceinline__ void gemm_body(
    SmemG& sm, int bx,
    const void* __restrict__ X,
    const unsigned short* __restrict__ Wt_g,
    const unsigned short* __restrict__ Ba_g,
    unsigned short* __restrict__ H, float* __restrict__ AS,
    float* __restrict__ AD, int nrows, int xf32)
{
  int tid = threadIdx.x;
#pragma unroll
  for (int i = 0; i < 8; i++) {
    int j = i * 256 + tid;        // 2048 16B chunks of W^T
    int c = j >> 4, k8 = j & 15;
    short8 v = *(const short8*)(Wt_g + c * 128 + k8 * 8);
    *(short8*)&sm.WB[c][k8 * 8] = v;
  }
  {
    int n = tid >> 4, k8 = tid & 15;   // Ba rows 128..143 (8..15 zeroed)
    short8 v = *(const short8*)(Ba_g + n * 128 + k8 * 8);
    *(short8*)&sm.WB[128 + n][k8 * 8] = v;
  }
  __syncthreads();
  int wave = tid >> 6, lane = tid & 63;
  int rt = bx * 4 + wave;
  if (rt * 16 >= nrows) return;
  int R0 = rt * 16;
  int m = lane & 15, quad = lane >> 4;
  size_t abase = (size_t)(R0 + m) * CH + quad * 8;
  float4v acc[8];
  float4v accA = (float4v){0.f, 0.f, 0.f, 0.f};
#pragma unroll
  for (int t = 0; t < 8; t++) acc[t] = (float4v){0.f, 0.f, 0.f, 0.f};
#pragma unroll
  for (int kb = 0; kb < 4; kb++) {
    short8 a = load_bf8(X, abase + kb * 32, xf32);
#pragma unroll
    for (int ct = 0; ct < 8; ct++) {
      short8 b = *(const short8*)&sm.WB[ct * 16 + m][kb * 32 + quad * 8];
      acc[ct] = __builtin_amdgcn_mfma_f32_16x16x32_bf16(a, b, acc[ct], 0, 0, 0);
    }
    short8 bA = *(const short8*)&sm.WB[128 + m][kb * 32 + quad * 8];
    accA = __builtin_amdgcn_mfma_f32_16x16x32_bf16(a, bA, accA, 0, 0, 0);
  }
  // H store (C/D layout col=ct*16+m, row=quad*4+r)
  int rbase = R0 + quad * 4;
#pragma unroll
  for (int ct = 0; ct < 8; ct++) {
    int col = ct * 16 + m;
#pragma unroll
    for (int r = 0; r < 4; r++)
      H[(size_t)(rbase + r) * CH + col] = __half_as_ushort(__float2half(acc[ct][r]));
  }
  // alpha store: accA col m = head (0..3 -> AS, 4..7 -> AD), row = quad*4+r
  if (m < 4) {
#pragma unroll
    for (int r = 0; r < 4; r++)
      AS[(size_t)(rbase + r) * 4 + m] = accA[r];
  } else if (m < 8) {
#pragma unroll
    for (int r = 0; r < 4; r++)
      AD[(size_t)(rbase + r) * 4 + (m - 4)] = accA[r];
  }
}

// layer-2 GEMM (standalone; X2 always bf16)
__global__ __launch_bounds__(256, 2) void k_gemm(
    const void* __restrict__ X,
    const unsigned short* __restrict__ Wt_g,
    const unsigned short* __restrict__ Ba_g,
    unsigned short* __restrict__ H, float* __restrict__ AS, float* __restrict__ AD,
    int nrows)
{
  __shared__ SmemG sm;
  gemm_body(sm, blockIdx.x, X, Wt_g, Ba_g, H, AS, AD, nrows, 0);
}

// layer-1 GEMM fused with bucket histogram (pass A)
__global__ __launch_bounds__(256, 2) void k_gemm_hist(
    const void* __restrict__ X,
    const unsigned short* __restrict__ Wt_g,
    const unsigned short* __restrict__ Ba_g,
    unsigned short* __restrict__ H, float* __restrict__ AS, float* __restrict__ AD,
    int nrows, const int* __restrict__ ei, int* __restrict__ MT,
    const int* __restrict__ flags)
{
  __shared__ SmemG sm;          // gemm blocks only
  __shared__ int hist[NBUCK];   // hist blocks only
  if (blockIdx.x >= GEMMB) {
    int b = blockIdx.x - GEMMB;
    int t = threadIdx.x;
    if (t < NBUCK) hist[t] = 0;
    __syncthreads();
    int i64 = flags[1];
    int base = b * EBLK;
#pragma unroll
    for (int k = 0; k < 8; k++) {
      int e = base + k * 256 + t;
      if (e < E_TOT) {
        int s, d;
        load_edge(ei, e, i64, s, d);
        atomicAdd(&hist[d >> 8], 1);
      }
    }
    __syncthreads();
    if (t < NBUCK) MT[t * MTP + b] = hist[t];
    return;
  }
  gemm_body(sm, blockIdx.x, X, Wt_g, Ba_g, H, AS, AD, nrows, flags[0]);
}

// pass B: exclusive-scan each MT row; T[q]=total
__global__ __launch_bounds__(512) void k_rowscan(int* __restrict__ MT,
                                                 int* __restrict__ T)
{
  __shared__ int sh[512];
  int q = blockIdx.x, t = threadIdx.x;
  int v = (t < NEB) ? MT[q * MTP + t] : 0;
  sh[t] = v;
  __syncthreads();
  for (int off = 1; off < 512; off <<= 1) {
    int u = (t >= off) ? sh[t - off] : 0;
    __syncthreads();
    sh[t] += u;
    __syncthreads();
  }
  if (t < NEB) MT[q * MTP + t] = sh[t] - v;
  if (t == NEB - 1) T[q] = sh[t];
}

// pass B2: exclusive-scan bucket totals
__global__ __launch_bounds__(256) void k_bscan(const int* __restrict__ T,
                                               int* __restrict__ BB)
{
  __shared__ int sh[256];
  int t = threadIdx.x;
  int v = (t < NBUCK) ? T[t] : 0;
  sh[t] = v;
  __syncthreads();
  for (int off = 1; off < 256; off <<= 1) {
    int u = (t >= off) ? sh[t - off] : 0;
    __syncthreads();
    sh[t] += u;
    __syncthreads();
  }
  if (t < NBUCK) BB[t] = sh[t] - v;
  if (t == NBUCK - 1) BB[NBUCK] = sh[t];
}

// pass C: scatter edges into bucket-ordered ebuf (LDS cursors)
__global__ __launch_bounds__(256) void k_bucket(
    const int* __restrict__ ei, const int* __restrict__ MT,
    const int* __restrict__ BB, int2* __restrict__ ebuf,
    const int* __restrict__ flags)
{
  __shared__ int cur[NBUCK];
  int b = blockIdx.x, t = threadIdx.x;
  if (t < NBUCK) cur[t] = BB[t] + MT[t * MTP + b];
  __syncthreads();
  int i64 = flags[1];
  int base = b * EBLK;
#pragma unroll
  for (int k = 0; k < 8; k++) {
    int e = base + k * 256 + t;
    if (e < E_TOT) {
      int s, d;
      load_edge(ei, e, i64, s, d);
      int pos = atomicAdd(&cur[d >> 8], 1);   // LDS atomic
      ebuf[pos] = make_int2(s, d);
    }
  }
}

// pass D: per-bucket fine CSR
__global__ __launch_bounds__(256) void k_fine(
    const int2* __restrict__ ebuf, const int* __restrict__ BB,
    int* __restrict__ row_ptr, int* __restrict__ deg,
    int* __restrict__ csr_src)
{
  __shared__ int cnt[256], sh[256], cur[256];
  int q = blockIdx.x, t = threadIdx.x;
  int lo = BB[q], hi = BB[q + 1];
  cnt[t] = 0;
  __syncthreads();
  for (int i = lo + t; i < hi; i += 256)
    atomicAdd(&cnt[ebuf[i].y & 255], 1);
  __syncthreads();
  int v = cnt[t];
  sh[t] = v;
  __syncthreads();
  for (int off = 1; off < 256; off <<= 1) {
    int u = (t >= off) ? sh[t - off] : 0;
    __syncthreads();
    sh[t] += u;
    __syncthreads();
  }
  int lp = sh[t] - v;
  int n = (q << 8) + t;
  if (n < N_NODES) { row_ptr[n] = lo + lp; deg[n] = v; }
  cur[t] = lo + lp;
  __syncthreads();
  for (int i = lo + t; i < hi; i += 256) {
    int2 p = ebuf[i];
    int slot = atomicAdd(&cur[p.y & 255], 1);   // LDS atomic
    csr_src[slot] = p.x;
  }
}

// ---- fused gather-aggregate + softmax + epilogue -------------------------
// Half-wave split: 32 lanes x 4 channels per edge; the wave processes 2
// edges per slot (hw = lane>>5), doubling vmem bytes/instr and edges in
// flight. Predicated 16-edge iterations (idx clamped, contribution zeroed)
// remove the serial scalar tail — mean deg 13.8 -> 1 iteration/node.
struct h2x2 { __half2 a, b; };

__global__ __launch_bounds__(256) void k_agg(
    const int* __restrict__ row_ptr, const int* __restrict__ deg,
    const int* __restrict__ csr_src,
    const __half* __restrict__ H,
    const float* __restrict__ AS, const float* __restrict__ AD,
    const void* __restrict__ b, void* __restrict__ Y,
    const int* __restrict__ flags, int layer)
{
  int tid = threadIdx.x;
  int node = blockIdx.x * 4 + (tid >> 6);
  if (node >= N_NODES) return;
  int lane = tid & 63;
  int hw = lane >> 5, ln = lane & 31;
  int h = ln >> 3;
  int c0 = 4 * ln;
  float adh = AD[(size_t)node * 4 + h];
  int start = row_ptr[node];
  int dg = deg[node];
  const h2x2* __restrict__ H4 = (const h2x2*)H;   // 8B chunks, 32 per row
  float a0 = 0.f, a1 = 0.f, a2 = 0.f, a3 = 0.f, den = 0.f;
  for (int j = 0; j < dg; j += 16) {
    int sI[8]; float pr[8];
#pragma unroll
    for (int u = 0; u < 8; u++) {
      int e = j + 2 * u + hw;
      int idx = e < dg ? e : dg - 1;
      sI[u] = csr_src[start + idx];
      pr[u] = e < dg ? 1.f : 0.f;
    }
    float eV[8];
#pragma unroll
    for (int u = 0; u < 8; u++) eV[u] = AS[(size_t)sI[u] * 4 + h] + adh;
    h2x2 hv[8];
#pragma unroll
    for (int u = 0; u < 8; u++) hv[u] = H4[(size_t)sI[u] * 32 + ln];
#pragma unroll
    for (int u = 0; u < 8; u++) {
      float x = eV[u] > 0.f ? eV[u] : 0.2f * eV[u];
      float ex = __expf(x) * pr[u];
      float2 f0 = __half22float2(hv[u].a);
      float2 f1 = __half22float2(hv[u].b);
      a0 += ex * f0.x;
      a1 += ex * f0.y;
      a2 += ex * f1.x;
      a3 += ex * f1.y;
      den += ex;
    }
  }
  // combine the two half-waves (even/odd edges of the same node)
  a0 += __shfl_xor(a0, 32);
  a1 += __shfl_xor(a1, 32);
  a2 += __shfl_xor(a2, 32);
  a3 += __shfl_xor(a3, 32);
  den += __shfl_xor(den, 32);
  if (hw) return;
  float inv = 1.f / (den + 1e-16f);
  int f32 = flags[0];
  float b0, b1, b2, b3;
  if (f32) {
    const float* bp = (const float*)b;
    b0 = bp[c0]; b1 = bp[c0 + 1]; b2 = bp[c0 + 2]; b3 = bp[c0 + 3];
  } else {
    const unsigned short* bp = (const unsigned short*)b;
    b0 = bf2f(bp[c0]); b1 = bf2f(bp[c0 + 1]);
    b2 = bf2f(bp[c0 + 2]); b3 = bf2f(bp[c0 + 3]);
  }
  float r0 = a0 * inv + b0;
  float r1 = a1 * inv + b1;
  float r2 = a2 * inv + b2;
  float r3 = a3 * inv + b3;
  size_t o = (size_t)node * CH + c0;
  if (layer == 1) {                 // relu + bf16 -> X2
    r0 = r0 > 0.f ? r0 : 0.f;
    r1 = r1 > 0.f ? r1 : 0.f;
    r2 = r2 > 0.f ? r2 : 0.f;
    r3 = r3 > 0.f ? r3 : 0.f;
    us4 w; w.x = f2bf(r0); w.y = f2bf(r1); w.z = f2bf(r2); w.w = f2bf(r3);
    *(us4*)((unsigned short*)Y + o) = w;
  } else if (f32) {
    float4 w; w.x = r0; w.y = r1; w.z = r2; w.w = r3;
    *(float4*)((float*)Y + o) = w;
  } else {
    us4 w; w.x = f2bf(r0); w.y = f2bf(r1); w.z = f2bf(r2); w.w = f2bf(r3);
    *(us4*)((unsigned short*)Y + o) = w;
  }
}

extern "C" void kernel_launch(void* const* d_in, const int* in_sizes, int n_in,
                              void* d_out, int out_size, void* d_ws, size_t ws_size,
                              hipStream_t stream)
{
  const void* x   = d_in[0];
  const int*  ei  = (const int*)d_in[1];
  const void* W1  = d_in[2];
  const void* as1 = d_in[3];
  const void* ad1 = d_in[4];
  const void* b1  = d_in[5];
  const void* W2  = d_in[6];
  const void* as2 = d_in[7];
  const void* ad2 = d_in[8];
  const void* b2  = d_in[9];

  char* ws = (char*)d_ws;
  unsigned short* H  = (unsigned short*)(ws);            // 12,800,000 B (fp16)
  float*  AS         = (float*)(ws + 12800000);          //    800,000 B
  float*  AD         = (float*)(ws + 13600000);          //    800,000 B
  unsigned short* X2 = (unsigned short*)(ws + 14400000); // 12,800,000 B
  int*    deg        = (int*)(ws + 27200000);            //    200,000 B
  int*    row_ptr    = (int*)(ws + 27400000);            //    200,000 B
  int*    csr_src    = (int*)(ws + 27600000);            //  2,760,000 B
  int*    MT         = (int*)(ws + 30360000);            //    269,696 B
  int*    T          = (int*)(ws + 30630000);            //        784 B
  int*    BB         = (int*)(ws + 30631000);            //        788 B
  int*    flags      = (int*)(ws + 30632000);            //         64 B
  int2*   ebuf       = (int2*)(ws + 30640000);           //  5,520,000 B
  unsigned short* Wt1 = (unsigned short*)(ws + 36160000); //    32,768 B
  unsigned short* Wt2 = (unsigned short*)(ws + 36200000); //    32,768 B
  unsigned short* Ba1 = (unsigned short*)(ws + 36240000); //     4,096 B
  unsigned short* Ba2 = (unsigned short*)(ws + 36248000); //     4,096 B

  const int agg_blocks = (N_NODES + 3) / 4;              // 1 wave per node

  k_detect<<<1, 256, 0, stream>>>((const unsigned short*)x,
                                  (const unsigned int*)ei, flags);
  k_prep<<<264, 256, 0, stream>>>(W1, W2, as1, ad1, as2, ad2,
                                  Wt1, Wt2, Ba1, Ba2, flags);

  // ---- layer-1 GEMM overlapped with bucket histogram (pass A) ----
  k_gemm_hist<<<GEMMB + NEB, 256, 0, stream>>>(
      x, Wt1, Ba1, H, AS, AD, N_NODES, ei, MT, flags);

  // ---- CSR build, atomic-free ----
  k_rowscan<<<NBUCK, 512, 0, stream>>>(MT, T);
  k_bscan  <<<1, 256, 0, stream>>>(T, BB);
  k_bucket <<<NEB, 256, 0, stream>>>(ei, MT, BB, ebuf, flags);
  k_fine   <<<NBUCK, 256, 0, stream>>>(ebuf, BB, row_ptr, deg, csr_src);

  // ---- layer 1 aggregate ----
  k_agg<<<agg_blocks, 256, 0, stream>>>(row_ptr, deg, csr_src,
                                        (const __half*)H, AS, AD,
                                        b1, X2, flags, 1);

  // ---- layer 2 ----
  k_gemm<<<GEMMB, 256, 0, stream>>>(X2, Wt2, Ba2, H, AS, AD, N_NODES);
  k_agg<<<agg_blocks, 256, 0, stream>>>(row_ptr, deg, csr_src,
                                        (const __half*)H, AS, AD,
                                        b2, d_out, flags, 2);
}